// Round 11
// baseline (48.091 us; speedup 1.0000x reference)
//
#include <hip/hip_runtime.h>
#include <hip/hip_bf16.h>
#include <math.h>

#define NROW 256
#define DIM  65536
#define LSTR 136            // LDS row stride in ushorts (128 + 8 pad, 16B-aligned)
#define PSP  32800          // partial stride in ushorts (32768 + 32 pad)

typedef __attribute__((ext_vector_type(8))) short short8;
typedef __attribute__((ext_vector_type(4))) float f32x4;
typedef unsigned int       u32t;
typedef unsigned long long u64t;

__device__ __forceinline__ float bf2f(ushort h) {
    u32t u = ((u32t)h) << 16;
    return __builtin_bit_cast(float, u);
}
// packed fp32x2 -> bf16x2 (v_cvt_pk_bf16_f32, RNE)
__device__ __forceinline__ u32t pk2(float lo, float hi) {
    __hip_bfloat162 h = __float22bfloat162_rn(make_float2(lo, hi));
    u32t r; __builtin_memcpy(&r, &h, 4); return r;
}

// native-layout index of G[i][j] (matches gemm epilogue store order)
__device__ __forceinline__ int gpos(int i, int j) {
    const int mh = i >> 7, il = i & 127;
    const int wid  = ((il >> 6) << 2) | (j >> 6);
    const int lane = (((il >> 2) & 3) << 4) | (j & 15);
    const int off  = ((wid << 6) | lane) * 64
                   + (((((il >> 4) & 3) << 2) | ((j >> 4) & 3)) << 2) + (il & 3);
    return mh * 32768 + off;
}

// ---------------------------------------------------------------------------
// Split-K x split-M MFMA GEMM, LONG-RUN reads: 256 blocks = 128 K-slices (s,
// 512 floats = 2 KB contiguous per row) x 2 row-halves (mh). Buddies (b,
// b+128) share the staged B-tile rows on the SAME XCD (b%8 == (b+128)%8).
// 4 chunks of k=128 (512 B per row per chunk, swept sequentially across
// chunks), double-buffered 139 KB LDS. Per chunk: issue next chunk's 16
// float4 -> 64 MFMAs on current buffer -> cvt_pk + ds_write other buffer ->
// one barrier. Output 128x256/block; bf16 partials, thread-native layout.
// ---------------------------------------------------------------------------
__global__ __launch_bounds__(512) void gemm_k(const float* __restrict__ E,
                                              ushort* __restrict__ part) {
    const int b   = blockIdx.x;
    const int s   = b & 127;            // k-slice (512 floats)
    const int mh  = b >> 7;             // row half
    const int tid  = threadIdx.x;
    const int lane = tid & 63;
    const int wid  = tid >> 6;
    const int wr   = wid >> 2;          // 0..1 -> 64-row band within half
    const int wc   = wid & 3;           // 0..3 -> 64-col band
    const int r15  = lane & 15;
    const int kgi  = lane >> 4;         // 0..3 -> 8-k slice within k=32

    __shared__ ushort es[2][NROW][LSTR];   // 139,264 B

    const int row = tid >> 1;           // staging row (2 threads/row)
    const int h   = tid & 1;            // 256B half of the 512B chunk-run
    const float* __restrict__ gb = E + ((size_t)row << 16) + s * 512 + h * 64;

    f32x4 acc[4][4];
    #pragma unroll
    for (int m = 0; m < 4; ++m)
        #pragma unroll
        for (int n = 0; n < 4; ++n) acc[m][n] = (f32x4){0.f, 0.f, 0.f, 0.f};

    auto LOADC = [&](int c, float4* v) {
        const float* p = gb + c * 128;
        #pragma unroll
        for (int u = 0; u < 16; ++u) v[u] = *(const float4*)(p + u * 4);
    };
    auto WRITEC = [&](int buf, const float4* v) {
        #pragma unroll
        for (int u = 0; u < 8; ++u) {
            uint4 q;
            q.x = pk2(v[2*u].x,   v[2*u].y);
            q.y = pk2(v[2*u].z,   v[2*u].w);
            q.z = pk2(v[2*u+1].x, v[2*u+1].y);
            q.w = pk2(v[2*u+1].z, v[2*u+1].w);
            *(uint4*)&es[buf][row][h * 64 + u * 8] = q;
        }
    };

    {
        float4 v0[16];
        LOADC(0, v0);
        WRITEC(0, v0);
    }

    #pragma unroll
    for (int c = 0; c < 4; ++c) {
        __syncthreads();                // buf (c&1) staged; prior reads done
        float4 vn[16];
        if (c < 3) LOADC(c + 1, vn);    // issue next chunk's loads early
        #pragma unroll
        for (int q = 0; q < 4; ++q) {   // 4 k-slices of 32 within the chunk
            const int ko = q * 32 + kgi * 8;
            short8 af[4], bfr[4];
            #pragma unroll
            for (int m = 0; m < 4; ++m)
                af[m] = *(const short8*)&es[c & 1][mh * 128 + wr * 64 + m * 16 + r15][ko];
            #pragma unroll
            for (int n = 0; n < 4; ++n)
                bfr[n] = *(const short8*)&es[c & 1][wc * 64 + n * 16 + r15][ko];
            #pragma unroll
            for (int m = 0; m < 4; ++m)
                #pragma unroll
                for (int n = 0; n < 4; ++n)
                    acc[m][n] = __builtin_amdgcn_mfma_f32_16x16x32_bf16(
                        af[m], bfr[n], acc[m][n], 0, 0, 0);
        }
        if (c < 3) WRITEC((c + 1) & 1, vn);   // waits vmcnt, fills other buf
    }

    // epilogue: 64 accs -> bf16, contiguous per-thread (coalesced 16B stores)
    ushort* pp = part + (size_t)(s * 2 + mh) * PSP + (size_t)tid * 64;
    #pragma unroll
    for (int m = 0; m < 4; ++m) {
        uint4 q1, q2;
        q1.x = pk2(acc[m][0][0], acc[m][0][1]);
        q1.y = pk2(acc[m][0][2], acc[m][0][3]);
        q1.z = pk2(acc[m][1][0], acc[m][1][1]);
        q1.w = pk2(acc[m][1][2], acc[m][1][3]);
        q2.x = pk2(acc[m][2][0], acc[m][2][1]);
        q2.y = pk2(acc[m][2][2], acc[m][2][3]);
        q2.z = pk2(acc[m][3][0], acc[m][3][1]);
        q2.w = pk2(acc[m][3][2], acc[m][3][3]);
        *(uint4*)(pp + m * 16)     = q1;
        *(uint4*)(pp + m * 16 + 8) = q2;
    }
}

// ---------------------------------------------------------------------------
// Reduce 128 partial pairs -> Gn (fp32, native layout). One position per
// thread, 128 s-values in 4 fixed-order quarters (deterministic tree).
// Also zeroes the fixed-point accumulator for row_loss (stream-ordered).
// ---------------------------------------------------------------------------
__global__ __launch_bounds__(256) void reduce_k(const ushort* __restrict__ part,
                                                float* __restrict__ Gn,
                                                u64t* __restrict__ acc,
                                                u32t* __restrict__ cnt) {
    if (blockIdx.x == 0 && threadIdx.x == 0) { *acc = 0ull; *cnt = 0u; }

    const int pos = blockIdx.x * 256 + threadIdx.x;   // 0..65535
    const int mh  = pos >> 15;
    const int off = pos & 32767;
    const ushort* base = part + (size_t)mh * PSP + off;

    float qs[4];
    #pragma unroll
    for (int qt = 0; qt < 4; ++qt) {
        float a = 0.f;
        #pragma unroll
        for (int s2 = 0; s2 < 32; ++s2) {
            const int s = qt * 32 + s2;
            a += bf2f(base[(size_t)(s * 2) * PSP]);
        }
        qs[qt] = a;
    }
    Gn[pos] = (qs[0] + qs[1]) + (qs[2] + qs[3]);
}

// ---------------------------------------------------------------------------
// Fused per-row softmax loss + deterministic final sum (fixed-point atomic,
// order-independent). PSD term provably 0 (AM-GM; clip at 0), omitted.
// ---------------------------------------------------------------------------
__global__ __launch_bounds__(256) void row_loss_k(const float* __restrict__ Gn,
                                                  const int* __restrict__ labels,
                                                  u64t* __restrict__ acc,
                                                  u32t* __restrict__ cnt,
                                                  float* __restrict__ out) {
    const int i = blockIdx.x;
    const int j = threadIdx.x;

    const float Gii = Gn[gpos(i, i)];
    const float Gjj = Gn[gpos(j, j)];
    const float Gij = Gn[gpos(i, j)];
    const float d2 = fmaxf(Gii + Gjj - 2.0f * Gij, 0.0f);
    const bool diag = (j == i);
    const float sc = diag ? -3.0e38f : -sqrtf(d2);

    __shared__ float red0[4], red1[4];

    float m = sc;
    #pragma unroll
    for (int off = 32; off; off >>= 1) m = fmaxf(m, __shfl_xor(m, off, 64));
    const int w = j >> 6;
    if ((j & 63) == 0) red0[w] = m;
    __syncthreads();
    m = fmaxf(fmaxf(red0[0], red0[1]), fmaxf(red0[2], red0[3]));

    const float p  = diag ? 0.0f : expf(sc - m);
    const float nm = (labels[j] == labels[i]) ? p : 0.0f;

    float zs = p, ns = nm;
    #pragma unroll
    for (int off = 32; off; off >>= 1) {
        zs += __shfl_xor(zs, off, 64);
        ns += __shfl_xor(ns, off, 64);
    }
    __syncthreads();
    if ((j & 63) == 0) { red0[w] = zs; red1[w] = ns; }
    __syncthreads();
    if (j == 0) {
        const float Z = red0[0] + red0[1] + red0[2] + red0[3];
        const float N = red1[0] + red1[1] + red1[2] + red1[3];
        const float rl = logf(Z) - logf(N);          // >= 0 (N subset of Z)
        const long long q = llrintf(rl * 1048576.0f);
        atomicAdd(acc, (u64t)q);
        __threadfence();
        const u32t c = atomicAdd(cnt, 1u);
        if (c == NROW - 1) {
            __threadfence();
            const u64t tot = atomicAdd(acc, 0ull);
            out[0] = (float)((double)(long long)tot * (1.0 / 1048576.0) * 0.005);
        }
    }
}

extern "C" void kernel_launch(void* const* d_in, const int* in_sizes, int n_in,
                              void* d_out, int out_size, void* d_ws, size_t ws_size,
                              hipStream_t stream) {
    const float* E      = (const float*)d_in[0];
    const int*   labels = (const int*)d_in[1];
    float*       out    = (float*)d_out;

    ushort* part = (ushort*)d_ws;                         // 256 * PSP ushorts
    float*  Gn   = (float*)((char*)d_ws + (size_t)256 * PSP * sizeof(ushort));
    u64t*   acc  = (u64t*)(Gn + 65536);
    u32t*   cnt  = (u32t*)(acc + 1);

    gemm_k    <<<256, 512, 0, stream>>>(E, part);
    reduce_k  <<<256, 256, 0, stream>>>(part, Gn, acc, cnt);
    row_loss_k<<<NROW, 256, 0, stream>>>(Gn, labels, acc, cnt, out);
}

// Round 12
// 44.853 us; speedup vs baseline: 1.0722x; 1.0722x over previous
//
#include <hip/hip_runtime.h>
#include <hip/hip_bf16.h>
#include <math.h>

#define NROW 256
#define DIM  65536
#define LSTR 264            // LDS row stride in ushorts (256 + 8 pad)
#define PSP  65600          // partial stride in ushorts (65536 + 64 pad)

typedef __attribute__((ext_vector_type(8))) short short8;
typedef __attribute__((ext_vector_type(4))) float f32x4;
typedef unsigned int       u32t;
typedef unsigned long long u64t;

__device__ __forceinline__ float bf2f(ushort h) {
    u32t u = ((u32t)h) << 16;
    return __builtin_bit_cast(float, u);
}
// packed fp32x2 -> bf16x2 (v_cvt_pk_bf16_f32, RNE)
__device__ __forceinline__ u32t pk2(float lo, float hi) {
    __hip_bfloat162 h = __float22bfloat162_rn(make_float2(lo, hi));
    u32t r; __builtin_memcpy(&r, &h, 4); return r;
}

// ---------------------------------------------------------------------------
// Split-K MFMA GEMM, FULLY-COALESCED global access.
// Block s owns k-slice [s*256, (s+1)*256).
//  Stage:  wave w loads rows [w*32, w*32+32); each instruction = 64 lanes x
//          16 B = 1 KB CONTIGUOUS from one row (8 x 128B lines, vs 64
//          scattered lines in all prior rounds). cvt_pk -> ds_write_b64
//          (512 B contiguous runs). One barrier.
//  MFMA:   8 k-steps, 8 waves x (128x64) tiles, acc[8][4] (128 VGPR).
//  Epilogue: acc -> LDS TRANSPOSE (es reused as [col][row]; j-regs are
//          row-consecutive -> uint2 packs natively), barrier, then each wave
//          streams 32 whole columns: 512 B contiguous stores. G symmetric
//          => storing G^T in plain [i][j] layout IS G. No gpos permutation.
// ---------------------------------------------------------------------------
__global__ __launch_bounds__(512) void gemm_k(const float* __restrict__ E,
                                              ushort* __restrict__ part) {
    const int s    = blockIdx.x;
    const int tid  = threadIdx.x;
    const int lane = tid & 63;
    const int wid  = tid >> 6;
    const int wr   = wid >> 2;          // 0..1 -> 128-row band
    const int wc   = wid & 3;           // 0..3 -> 64-col band
    const int r15  = lane & 15;
    const int kgi  = lane >> 4;         // 0..3 -> 8-k slice within k=32

    __shared__ ushort es[NROW][LSTR];   // 135 KB; staging, then transpose buf

    // ---------------- stage: coalesced 1 KB row reads ----------------
    {
        const int wrow = wid * 32;
        float4 v[32];
        #pragma unroll
        for (int i = 0; i < 32; ++i) {
            const int row = wrow + i;
            v[i] = *(const float4*)(E + ((size_t)row << 16)
                                      + (size_t)s * 256 + lane * 4);
        }
        #pragma unroll
        for (int i = 0; i < 32; ++i) {
            const int row = wrow + i;
            uint2 wv;
            wv.x = pk2(v[i].x, v[i].y);
            wv.y = pk2(v[i].z, v[i].w);
            *(uint2*)&es[row][lane * 4] = wv;
        }
    }
    __syncthreads();

    // ---------------- MFMA: 8 k-steps of K=32 ----------------
    f32x4 acc[8][4];
    #pragma unroll
    for (int m = 0; m < 8; ++m)
        #pragma unroll
        for (int n = 0; n < 4; ++n) acc[m][n] = (f32x4){0.f, 0.f, 0.f, 0.f};

    #pragma unroll
    for (int kk = 0; kk < 8; ++kk) {
        const int ko = kk * 32 + kgi * 8;
        short8 af[8], bfr[4];
        #pragma unroll
        for (int m = 0; m < 8; ++m)
            af[m] = *(const short8*)&es[wr * 128 + m * 16 + r15][ko];
        #pragma unroll
        for (int n = 0; n < 4; ++n)
            bfr[n] = *(const short8*)&es[wc * 64 + n * 16 + r15][ko];
        #pragma unroll
        for (int m = 0; m < 8; ++m)
            #pragma unroll
            for (int n = 0; n < 4; ++n)
                acc[m][n] = __builtin_amdgcn_mfma_f32_16x16x32_bf16(
                    af[m], bfr[n], acc[m][n], 0, 0, 0);
    }

    __syncthreads();    // all frag reads done; es reusable as [col][row]

    // ---------------- epilogue: LDS transpose ----------------
    const int rq = (lane >> 4) * 4;     // row-quad base within 16-row block
    #pragma unroll
    for (int m = 0; m < 8; ++m)
        #pragma unroll
        for (int n = 0; n < 4; ++n) {
            const int col  = wc * 64 + n * 16 + r15;
            const int rowb = wr * 128 + m * 16 + rq;
            uint2 wv;
            wv.x = pk2(acc[m][n][0], acc[m][n][1]);
            wv.y = pk2(acc[m][n][2], acc[m][n][3]);
            *(uint2*)&es[col][rowb] = wv;   // es viewed as [col][row]
        }
    __syncthreads();

    // coalesced store-out: wave w streams cols [w*32, w*32+32)
    ushort* pb = part + (size_t)s * PSP;
    #pragma unroll
    for (int i = 0; i < 32; ++i) {
        const int col = wid * 32 + i;
        const uint2 q = *(const uint2*)&es[col][lane * 4];
        *(uint2*)(pb + col * 256 + lane * 4) = q;
    }
}

// ---------------------------------------------------------------------------
// Reduce 256 bf16 partials -> Gn (fp32, PLAIN [i*256+j] layout). One position
// per thread; 8 fixed-order groups of 32 (deterministic tree). Wave access =
// 64 lanes x 2 B contiguous = one 128 B line per s. Also zeroes the
// fixed-point accumulator for row_loss (stream-ordered).
// ---------------------------------------------------------------------------
__global__ __launch_bounds__(256) void reduce_k(const ushort* __restrict__ part,
                                                float* __restrict__ Gn,
                                                u64t* __restrict__ acc,
                                                u32t* __restrict__ cnt) {
    if (blockIdx.x == 0 && threadIdx.x == 0) { *acc = 0ull; *cnt = 0u; }

    const int pos = blockIdx.x * 256 + threadIdx.x;   // 0..65535
    const ushort* base = part + pos;

    float g[8];
    #pragma unroll
    for (int q = 0; q < 8; ++q) {
        float a = 0.f;
        #pragma unroll
        for (int u = 0; u < 32; ++u)
            a += bf2f(base[(size_t)(q * 32 + u) * PSP]);
        g[q] = a;
    }
    Gn[pos] = ((g[0] + g[1]) + (g[2] + g[3])) + ((g[4] + g[5]) + (g[6] + g[7]));
}

// ---------------------------------------------------------------------------
// Fused per-row softmax loss + deterministic final sum (fixed-point atomic,
// order-independent). PSD term provably 0 (AM-GM; clip at 0), omitted.
// ---------------------------------------------------------------------------
__global__ __launch_bounds__(256) void row_loss_k(const float* __restrict__ Gn,
                                                  const int* __restrict__ labels,
                                                  u64t* __restrict__ acc,
                                                  u32t* __restrict__ cnt,
                                                  float* __restrict__ out) {
    const int i = blockIdx.x;
    const int j = threadIdx.x;

    const float Gii = Gn[i * 256 + i];
    const float Gjj = Gn[j * 256 + j];
    const float Gij = Gn[i * 256 + j];
    const float d2 = fmaxf(Gii + Gjj - 2.0f * Gij, 0.0f);
    const bool diag = (j == i);
    const float sc = diag ? -3.0e38f : -sqrtf(d2);

    __shared__ float red0[4], red1[4];

    float m = sc;
    #pragma unroll
    for (int off = 32; off; off >>= 1) m = fmaxf(m, __shfl_xor(m, off, 64));
    const int w = j >> 6;
    if ((j & 63) == 0) red0[w] = m;
    __syncthreads();
    m = fmaxf(fmaxf(red0[0], red0[1]), fmaxf(red0[2], red0[3]));

    const float p  = diag ? 0.0f : expf(sc - m);
    const float nm = (labels[j] == labels[i]) ? p : 0.0f;

    float zs = p, ns = nm;
    #pragma unroll
    for (int off = 32; off; off >>= 1) {
        zs += __shfl_xor(zs, off, 64);
        ns += __shfl_xor(ns, off, 64);
    }
    __syncthreads();
    if ((j & 63) == 0) { red0[w] = zs; red1[w] = ns; }
    __syncthreads();
    if (j == 0) {
        const float Z = red0[0] + red0[1] + red0[2] + red0[3];
        const float N = red1[0] + red1[1] + red1[2] + red1[3];
        const float rl = logf(Z) - logf(N);          // >= 0 (N subset of Z)
        const long long q = llrintf(rl * 1048576.0f);
        atomicAdd(acc, (u64t)q);
        __threadfence();
        const u32t c = atomicAdd(cnt, 1u);
        if (c == NROW - 1) {
            __threadfence();
            const u64t tot = atomicAdd(acc, 0ull);
            out[0] = (float)((double)(long long)tot * (1.0 / 1048576.0) * 0.005);
        }
    }
}

extern "C" void kernel_launch(void* const* d_in, const int* in_sizes, int n_in,
                              void* d_out, int out_size, void* d_ws, size_t ws_size,
                              hipStream_t stream) {
    const float* E      = (const float*)d_in[0];
    const int*   labels = (const int*)d_in[1];
    float*       out    = (float*)d_out;

    ushort* part = (ushort*)d_ws;                         // 256 * PSP ushorts
    float*  Gn   = (float*)((char*)d_ws + (size_t)256 * PSP * sizeof(ushort));
    u64t*   acc  = (u64t*)(Gn + 65536);
    u32t*   cnt  = (u32t*)(acc + 1);

    gemm_k    <<<256, 512, 0, stream>>>(E, part);
    reduce_k  <<<256, 256, 0, stream>>>(part, Gn, acc, cnt);
    row_loss_k<<<NROW, 256, 0, stream>>>(Gn, labels, acc, cnt, out);
}

// Round 14
// 43.532 us; speedup vs baseline: 1.1047x; 1.0304x over previous
//
#include <hip/hip_runtime.h>
#include <hip/hip_bf16.h>
#include <math.h>

#define NROW 256
#define DIM  65536
#define LSTR 264            // LDS row stride in ushorts (256 + 8 pad)
#define PSP  65600          // partial stride in ushorts (65536 + 64 pad)

typedef __attribute__((ext_vector_type(8))) short short8;
typedef __attribute__((ext_vector_type(4))) float f32x4;
typedef __attribute__((ext_vector_type(4))) float ef4;       // nt-compatible
typedef __attribute__((ext_vector_type(2))) unsigned int eu2; // nt-compatible
typedef unsigned int       u32t;
typedef unsigned long long u64t;

__device__ __forceinline__ float bf2f(ushort h) {
    u32t u = ((u32t)h) << 16;
    return __builtin_bit_cast(float, u);
}
// packed fp32x2 -> bf16x2 (v_cvt_pk_bf16_f32, RNE)
__device__ __forceinline__ u32t pk2(float lo, float hi) {
    __hip_bfloat162 h = __float22bfloat162_rn(make_float2(lo, hi));
    u32t r; __builtin_memcpy(&r, &h, 4); return r;
}

// ---------------------------------------------------------------------------
// Split-K MFMA GEMM, fully-coalesced, ALL global access NON-TEMPORAL
// (nt: no L3 allocate -> no dirty-poison eviction writebacks; the harness
// poisons 268 MB of d_ws between replays, filling L3 with dirty lines that
// every normal allocate would have to write back to HBM).
// Structure identical to round 12:
//  Stage:  wave w rows [w*32,+32); 1 instr = 64 lanes x 16 B = 1 KB
//          contiguous per row; cvt_pk -> ds_write_b64. One barrier.
//  MFMA:   8 k-steps, 8 waves x (128x64), acc[8][4].
//  Epilogue: acc -> LDS transpose -> coalesced nt stores of whole columns.
//          G symmetric => storing G^T in plain [i][j] IS G.
// ---------------------------------------------------------------------------
__global__ __launch_bounds__(512) void gemm_k(const float* __restrict__ E,
                                              ushort* __restrict__ part) {
    const int s    = blockIdx.x;
    const int tid  = threadIdx.x;
    const int lane = tid & 63;
    const int wid  = tid >> 6;
    const int wr   = wid >> 2;          // 0..1 -> 128-row band
    const int wc   = wid & 3;           // 0..3 -> 64-col band
    const int r15  = lane & 15;
    const int kgi  = lane >> 4;         // 0..3 -> 8-k slice within k=32

    __shared__ ushort es[NROW][LSTR];   // 135 KB; staging, then transpose buf

    // ---------------- stage: coalesced 1 KB row reads (nt) ----------------
    {
        const int wrow = wid * 32;
        ef4 v[32];
        #pragma unroll
        for (int i = 0; i < 32; ++i) {
            const int row = wrow + i;
            v[i] = __builtin_nontemporal_load(
                (const ef4*)(E + ((size_t)row << 16)
                               + (size_t)s * 256 + lane * 4));
        }
        #pragma unroll
        for (int i = 0; i < 32; ++i) {
            const int row = wrow + i;
            eu2 wv;
            wv.x = pk2(v[i].x, v[i].y);
            wv.y = pk2(v[i].z, v[i].w);
            *(eu2*)&es[row][lane * 4] = wv;
        }
    }
    __syncthreads();

    // ---------------- MFMA: 8 k-steps of K=32 ----------------
    f32x4 acc[8][4];
    #pragma unroll
    for (int m = 0; m < 8; ++m)
        #pragma unroll
        for (int n = 0; n < 4; ++n) acc[m][n] = (f32x4){0.f, 0.f, 0.f, 0.f};

    #pragma unroll
    for (int kk = 0; kk < 8; ++kk) {
        const int ko = kk * 32 + kgi * 8;
        short8 af[8], bfr[4];
        #pragma unroll
        for (int m = 0; m < 8; ++m)
            af[m] = *(const short8*)&es[wr * 128 + m * 16 + r15][ko];
        #pragma unroll
        for (int n = 0; n < 4; ++n)
            bfr[n] = *(const short8*)&es[wc * 64 + n * 16 + r15][ko];
        #pragma unroll
        for (int m = 0; m < 8; ++m)
            #pragma unroll
            for (int n = 0; n < 4; ++n)
                acc[m][n] = __builtin_amdgcn_mfma_f32_16x16x32_bf16(
                    af[m], bfr[n], acc[m][n], 0, 0, 0);
    }

    __syncthreads();    // all frag reads done; es reusable as [col][row]

    // ---------------- epilogue: LDS transpose ----------------
    const int rq = (lane >> 4) * 4;     // row-quad base within 16-row block
    #pragma unroll
    for (int m = 0; m < 8; ++m)
        #pragma unroll
        for (int n = 0; n < 4; ++n) {
            const int col  = wc * 64 + n * 16 + r15;
            const int rowb = wr * 128 + m * 16 + rq;
            eu2 wv;
            wv.x = pk2(acc[m][n][0], acc[m][n][1]);
            wv.y = pk2(acc[m][n][2], acc[m][n][3]);
            *(eu2*)&es[col][rowb] = wv;   // es viewed as [col][row]
        }
    __syncthreads();

    // coalesced nt store-out: wave w streams cols [w*32, w*32+32)
    ushort* pb = part + (size_t)s * PSP;
    #pragma unroll
    for (int i = 0; i < 32; ++i) {
        const int col = wid * 32 + i;
        const eu2 q = *(const eu2*)&es[col][lane * 4];
        __builtin_nontemporal_store(q, (eu2*)(pb + col * 256 + lane * 4));
    }
}

// ---------------------------------------------------------------------------
// Reduce 256 bf16 partials -> Gn (fp32, PLAIN [i*256+j] layout), nt reads.
// One position per thread; 8 fixed-order groups of 32 (deterministic tree).
// Also zeroes the fixed-point accumulator for row_loss (stream-ordered).
// ---------------------------------------------------------------------------
__global__ __launch_bounds__(256) void reduce_k(const ushort* __restrict__ part,
                                                float* __restrict__ Gn,
                                                u64t* __restrict__ acc,
                                                u32t* __restrict__ cnt) {
    if (blockIdx.x == 0 && threadIdx.x == 0) { *acc = 0ull; *cnt = 0u; }

    const int pos = blockIdx.x * 256 + threadIdx.x;   // 0..65535
    const ushort* base = part + pos;

    float g[8];
    #pragma unroll
    for (int q = 0; q < 8; ++q) {
        float a = 0.f;
        #pragma unroll
        for (int u = 0; u < 32; ++u)
            a += bf2f(__builtin_nontemporal_load(
                          base + (size_t)(q * 32 + u) * PSP));
        g[q] = a;
    }
    Gn[pos] = ((g[0] + g[1]) + (g[2] + g[3])) + ((g[4] + g[5]) + (g[6] + g[7]));
}

// ---------------------------------------------------------------------------
// Fused per-row softmax loss + deterministic final sum (fixed-point atomic,
// order-independent). PSD term provably 0 (AM-GM; clip at 0), omitted.
// ---------------------------------------------------------------------------
__global__ __launch_bounds__(256) void row_loss_k(const float* __restrict__ Gn,
                                                  const int* __restrict__ labels,
                                                  u64t* __restrict__ acc,
                                                  u32t* __restrict__ cnt,
                                                  float* __restrict__ out) {
    const int i = blockIdx.x;
    const int j = threadIdx.x;

    const float Gii = Gn[i * 256 + i];
    const float Gjj = Gn[j * 256 + j];
    const float Gij = Gn[i * 256 + j];
    const float d2 = fmaxf(Gii + Gjj - 2.0f * Gij, 0.0f);
    const bool diag = (j == i);
    const float sc = diag ? -3.0e38f : -sqrtf(d2);

    __shared__ float red0[4], red1[4];

    float m = sc;
    #pragma unroll
    for (int off = 32; off; off >>= 1) m = fmaxf(m, __shfl_xor(m, off, 64));
    const int w = j >> 6;
    if ((j & 63) == 0) red0[w] = m;
    __syncthreads();
    m = fmaxf(fmaxf(red0[0], red0[1]), fmaxf(red0[2], red0[3]));

    const float p  = diag ? 0.0f : expf(sc - m);
    const float nm = (labels[j] == labels[i]) ? p : 0.0f;

    float zs = p, ns = nm;
    #pragma unroll
    for (int off = 32; off; off >>= 1) {
        zs += __shfl_xor(zs, off, 64);
        ns += __shfl_xor(ns, off, 64);
    }
    __syncthreads();
    if ((j & 63) == 0) { red0[w] = zs; red1[w] = ns; }
    __syncthreads();
    if (j == 0) {
        const float Z = red0[0] + red0[1] + red0[2] + red0[3];
        const float N = red1[0] + red1[1] + red1[2] + red1[3];
        const float rl = logf(Z) - logf(N);          // >= 0 (N subset of Z)
        const long long q = llrintf(rl * 1048576.0f);
        atomicAdd(acc, (u64t)q);
        __threadfence();
        const u32t c = atomicAdd(cnt, 1u);
        if (c == NROW - 1) {
            __threadfence();
            const u64t tot = atomicAdd(acc, 0ull);
            out[0] = (float)((double)(long long)tot * (1.0 / 1048576.0) * 0.005);
        }
    }
}

extern "C" void kernel_launch(void* const* d_in, const int* in_sizes, int n_in,
                              void* d_out, int out_size, void* d_ws, size_t ws_size,
                              hipStream_t stream) {
    const float* E      = (const float*)d_in[0];
    const int*   labels = (const int*)d_in[1];
    float*       out    = (float*)d_out;

    ushort* part = (ushort*)d_ws;                         // 256 * PSP ushorts
    float*  Gn   = (float*)((char*)d_ws + (size_t)256 * PSP * sizeof(ushort));
    u64t*   acc  = (u64t*)(Gn + 65536);
    u32t*   cnt  = (u32t*)(acc + 1);

    gemm_k    <<<256, 512, 0, stream>>>(E, part);
    reduce_k  <<<256, 256, 0, stream>>>(part, Gn, acc, cnt);
    row_loss_k<<<NROW, 256, 0, stream>>>(Gn, labels, acc, cnt, out);
}